// Round 1
// baseline (150117.419 us; speedup 1.0000x reference)
//
#include <hip/hip_runtime.h>
#include <math.h>

#define BB 32
#define TT 2048
#define II 128
#define NN 1024

#define NWG 256        // 64 i-blocks x 4 j-groups
#define NTHR 512
#define R_PER_WG 16    // W rows per WG
#define B_PER_J 8      // batch elements per j-group
#define KW 64          // W k-chunk per thread (16-way k split)
#define KU 8           // W_in k-chunk per thread

// LDS h row: 1024 floats stored as 16 chunks of 68 (pad breaks 16-way bank conflict -> 2-way, free)
#define CHUNK 68
#define HPAD (16 * CHUNK)   // 1088

__global__ __launch_bounds__(NTHR) void esn_kernel(
    const float* __restrict__ u, const float* __restrict__ w_in,
    const float* __restrict__ w, const float* __restrict__ w_bias,
    float* __restrict__ out, unsigned int* __restrict__ flags)
{
    __shared__ alignas(16) float h_stage[B_PER_J * HPAD];  // 34816 B
    __shared__ alignas(16) float u_stage[B_PER_J * II];    // 4096 B

    const int tid = threadIdx.x;
    const int wg  = blockIdx.x;
    const int ig  = wg & 63;          // i-block (rows ig*16 .. +16)
    const int jg  = wg >> 6;          // j-group (batches jg*8 .. +8)
    const int b2  = tid >> 8;         // 0..1
    const int r   = (tid >> 4) & 15;  // 0..15
    const int ks  = tid & 15;         // 0..15 (k split)
    const int lane = tid & 63;
    const int n   = ig * R_PER_WG + r;

    // W slice -> registers: W[n][ks*64 .. +64)
    float4 wreg[16];
    {
        const float* wrow = w + (size_t)n * NN + ks * KW;
        #pragma unroll
        for (int q = 0; q < 16; ++q)
            wreg[q] = reinterpret_cast<const float4*>(wrow)[q];
    }
    // W_in slice -> registers: W_in[n][ks*8 .. +8)
    float4 wir0, wir1;
    {
        const float* wirow = w_in + n * II + ks * KU;
        wir0 = reinterpret_cast<const float4*>(wirow)[0];
        wir1 = reinterpret_cast<const float4*>(wirow)[1];
    }
    const float bias = w_bias[n];

    unsigned int* gflags = flags + jg * 64;

    for (int t = 0; t < TT; ++t) {
        __syncthreads();  // previous step's LDS readers done before restaging

        // stage u[jg*8 .. +8][t][:] (1024 floats, 2/thread) -- independent of h, overlaps poll wait
        #pragma unroll
        for (int c = 0; c < 2; ++c) {
            int idx = c * NTHR + tid;     // 0..1023
            int bl  = idx >> 7;
            int k2  = idx & 127;
            int bg  = jg * B_PER_J + bl;
            u_stage[bl * II + k2] = u[((size_t)bg * TT + t) * II + k2];
        }

        if (t > 0) {
            // wait for all 64 producers of this j-group to finish step t-1
            for (;;) {
                unsigned int v = __hip_atomic_load(&gflags[lane], __ATOMIC_RELAXED,
                                                   __HIP_MEMORY_SCOPE_AGENT);
                if (__all((int)(v >= (unsigned)t))) break;
                __builtin_amdgcn_s_sleep(1);
            }
            __threadfence();  // acquire: inv L1/L2 so h loads below see IC-fresh data

            // stage h_{t-1}[8][1024] from d_out (8192 floats, 4 float4/thread, coalesced)
            #pragma unroll
            for (int c = 0; c < 4; ++c) {
                int f4 = c * NTHR + tid;      // 0..2047
                int bl = f4 >> 8;
                int k  = (f4 & 255) * 4;
                int bg = jg * B_PER_J + bl;
                float4 hv = reinterpret_cast<const float4*>(
                                out + ((size_t)bg * TT + (t - 1)) * NN)[f4 & 255];
                *reinterpret_cast<float4*>(
                    &h_stage[bl * HPAD + (k >> 6) * CHUNK + (k & 63)]) = hv;
            }
        }
        __syncthreads();

        float acc[4] = {0.f, 0.f, 0.f, 0.f};

        // W_in . u  (k2 = ks*8 .. +8)
        #pragma unroll
        for (int m = 0; m < 4; ++m) {
            int bl = b2 * 4 + m;
            const float* ub = &u_stage[bl * II + ks * KU];
            float4 u0 = reinterpret_cast<const float4*>(ub)[0];
            float4 u1 = reinterpret_cast<const float4*>(ub)[1];
            acc[m] += wir0.x * u0.x + wir0.y * u0.y + wir0.z * u0.z + wir0.w * u0.w
                    + wir1.x * u1.x + wir1.y * u1.y + wir1.z * u1.z + wir1.w * u1.w;
        }

        // W . h_{t-1}  (k = ks*64 .. +64)
        if (t > 0) {
            #pragma unroll
            for (int q = 0; q < 16; ++q) {
                float4 wv = wreg[q];
                #pragma unroll
                for (int m = 0; m < 4; ++m) {
                    int bl = b2 * 4 + m;
                    float4 hv = *reinterpret_cast<const float4*>(
                        &h_stage[bl * HPAD + ks * CHUNK + q * 4]);
                    acc[m] += wv.x * hv.x + wv.y * hv.y + wv.z * hv.z + wv.w * hv.w;
                }
            }
        }

        // reduce across the 16 k-split lanes (tid bits 0..3)
        #pragma unroll
        for (int m = 0; m < 4; ++m) {
            float a = acc[m];
            a += __shfl_xor(a, 1);
            a += __shfl_xor(a, 2);
            a += __shfl_xor(a, 4);
            a += __shfl_xor(a, 8);
            acc[m] = a;
        }

        if (ks == 0) {
            #pragma unroll
            for (int m = 0; m < 4; ++m) {
                int bl = b2 * 4 + m;
                int bg = jg * B_PER_J + bl;
                float hval = tanhf(acc[m] + bias);
                out[((size_t)bg * TT + t) * NN + n] = hval;
            }
        }

        __threadfence();   // release: per-wave vmcnt(0) + wbl2 -> h_t reaches IC
        __syncthreads();
        if (tid == 0) {
            __hip_atomic_store(&gflags[ig], (unsigned)(t + 1), __ATOMIC_RELEASE,
                               __HIP_MEMORY_SCOPE_AGENT);
        }
    }
}

extern "C" void kernel_launch(void* const* d_in, const int* in_sizes, int n_in,
                              void* d_out, int out_size, void* d_ws, size_t ws_size,
                              hipStream_t stream) {
    const float* u      = (const float*)d_in[0];
    const float* w_in   = (const float*)d_in[1];
    const float* w      = (const float*)d_in[2];
    const float* w_bias = (const float*)d_in[3];
    float* out          = (float*)d_out;
    unsigned int* flags = (unsigned int*)d_ws;

    // zero the 4x64 producer flags every call (ws is poisoned once, never re-poisoned)
    hipMemsetAsync(flags, 0, 4 * 64 * sizeof(unsigned int), stream);

    // 256 WGs x 512 threads: worst-case packing still fits 2 WGs/CU
    // (38 KB LDS, ~120 VGPR) so all 256 are co-resident -> flag spin cannot deadlock.
    esn_kernel<<<dim3(NWG), dim3(NTHR), 0, stream>>>(u, w_in, w, w_bias, out, flags);
}

// Round 2
// 21248.361 us; speedup vs baseline: 7.0649x; 7.0649x over previous
//
#include <hip/hip_runtime.h>
#include <math.h>

#define BB 32
#define TT 2048
#define II 128
#define NN 1024

#define NWG 256        // 64 i-blocks x 4 j-groups
#define NTHR 512
#define R_PER_WG 16    // W rows per WG
#define B_PER_J 8      // batch elements per j-group
#define KW 64          // W k-chunk per thread (16-way k split)
#define KU 8           // W_in k-chunk per thread

// LDS h row: 1024 floats stored as 16 chunks of 68 (pad breaks 16-way bank conflict -> 2-way, free)
#define CHUNK 68
#define HPAD (16 * CHUNK)   // 1088

__global__ __launch_bounds__(NTHR) void esn_kernel(
    const float* __restrict__ u, const float* __restrict__ w_in,
    const float* __restrict__ w, const float* __restrict__ w_bias,
    float* __restrict__ out, unsigned int* __restrict__ flags)
{
    __shared__ alignas(16) float h_stage[B_PER_J * HPAD];  // 34816 B
    __shared__ alignas(16) float u_stage[B_PER_J * II];    // 4096 B

    const int tid = threadIdx.x;
    const int wg  = blockIdx.x;
    const int ig  = wg & 63;          // i-block (rows ig*16 .. +16)
    const int jg  = wg >> 6;          // j-group (batches jg*8 .. +8)
    const int b2  = tid >> 8;         // 0..1
    const int r   = (tid >> 4) & 15;  // 0..15
    const int ks  = tid & 15;         // 0..15 (k split)
    const int lane = tid & 63;
    const int n   = ig * R_PER_WG + r;

    // W slice -> registers: W[n][ks*64 .. +64)
    float4 wreg[16];
    {
        const float* wrow = w + (size_t)n * NN + ks * KW;
        #pragma unroll
        for (int q = 0; q < 16; ++q)
            wreg[q] = reinterpret_cast<const float4*>(wrow)[q];
    }
    // W_in slice -> registers: W_in[n][ks*8 .. +8)
    float4 wir0, wir1;
    {
        const float* wirow = w_in + n * II + ks * KU;
        wir0 = reinterpret_cast<const float4*>(wirow)[0];
        wir1 = reinterpret_cast<const float4*>(wirow)[1];
    }
    const float bias = w_bias[n];

    unsigned int* gflags = flags + jg * 64;

    for (int t = 0; t < TT; ++t) {
        __syncthreads();  // previous step's LDS readers done before restaging

        // stage u[jg*8 .. +8][t][:] (1024 floats, 2/thread) -- plain cached loads (read-only data)
        #pragma unroll
        for (int c = 0; c < 2; ++c) {
            int idx = c * NTHR + tid;     // 0..1023
            int bl  = idx >> 7;
            int k2  = idx & 127;
            int bg  = jg * B_PER_J + bl;
            u_stage[bl * II + k2] = u[((size_t)bg * TT + t) * II + k2];
        }

        if (t > 0) {
            // wait for all 64 producers of this j-group to finish step t-1
            for (;;) {
                unsigned int v = __hip_atomic_load(&gflags[lane], __ATOMIC_RELAXED,
                                                   __HIP_MEMORY_SCOPE_AGENT);
                if (__all((int)(v >= (unsigned)t))) break;
                __builtin_amdgcn_s_sleep(1);
            }
            asm volatile("" ::: "memory");  // no hoisting of h loads above the poll

            // stage h_{t-1}[8][1024]: relaxed agent atomic loads = global_load_dword sc1
            // (forced L1/L2 miss -> IC-coherent; NO buffer_inv needed)
            #pragma unroll
            for (int c = 0; c < 16; ++c) {
                int idx = c * NTHR + tid;      // 0..8191
                int bl  = idx >> 10;
                int k   = idx & 1023;
                int bg  = jg * B_PER_J + bl;
                float hv = __hip_atomic_load(
                    out + ((size_t)bg * TT + (t - 1)) * NN + k,
                    __ATOMIC_RELAXED, __HIP_MEMORY_SCOPE_AGENT);
                h_stage[bl * HPAD + (k >> 6) * CHUNK + (k & 63)] = hv;
            }
        }
        __syncthreads();

        float acc[4] = {0.f, 0.f, 0.f, 0.f};

        // W_in . u  (k2 = ks*8 .. +8)
        #pragma unroll
        for (int m = 0; m < 4; ++m) {
            int bl = b2 * 4 + m;
            const float* ub = &u_stage[bl * II + ks * KU];
            float4 u0 = reinterpret_cast<const float4*>(ub)[0];
            float4 u1 = reinterpret_cast<const float4*>(ub)[1];
            acc[m] += wir0.x * u0.x + wir0.y * u0.y + wir0.z * u0.z + wir0.w * u0.w
                    + wir1.x * u1.x + wir1.y * u1.y + wir1.z * u1.z + wir1.w * u1.w;
        }

        // W . h_{t-1}  (k = ks*64 .. +64)
        if (t > 0) {
            #pragma unroll
            for (int q = 0; q < 16; ++q) {
                float4 wv = wreg[q];
                #pragma unroll
                for (int m = 0; m < 4; ++m) {
                    int bl = b2 * 4 + m;
                    float4 hv = *reinterpret_cast<const float4*>(
                        &h_stage[bl * HPAD + ks * CHUNK + q * 4]);
                    acc[m] += wv.x * hv.x + wv.y * hv.y + wv.z * hv.z + wv.w * hv.w;
                }
            }
        }

        // reduce across the 16 k-split lanes (tid bits 0..3)
        #pragma unroll
        for (int m = 0; m < 4; ++m) {
            float a = acc[m];
            a += __shfl_xor(a, 1);
            a += __shfl_xor(a, 2);
            a += __shfl_xor(a, 4);
            a += __shfl_xor(a, 8);
            acc[m] = a;
        }

        if (ks == 0) {
            #pragma unroll
            for (int m = 0; m < 4; ++m) {
                int bl = b2 * 4 + m;
                int bg = jg * B_PER_J + bl;
                float hval = tanhf(acc[m] + bias);
                // relaxed agent atomic store = global_store_dword sc1 (write-through
                // to IC, device-visible once vmcnt retires; NO buffer_wbl2)
                __hip_atomic_store(out + ((size_t)bg * TT + t) * NN + n, hval,
                                   __ATOMIC_RELAXED, __HIP_MEMORY_SCOPE_AGENT);
            }
        }

        // this wave's sc1 stores are device-visible once vmcnt(0) retires
        asm volatile("s_waitcnt vmcnt(0)" ::: "memory");
        __syncthreads();   // all waves' stores drained before the flag goes up
        if (tid == 0) {
            __hip_atomic_store(&gflags[ig], (unsigned)(t + 1), __ATOMIC_RELAXED,
                               __HIP_MEMORY_SCOPE_AGENT);
        }
    }
}

extern "C" void kernel_launch(void* const* d_in, const int* in_sizes, int n_in,
                              void* d_out, int out_size, void* d_ws, size_t ws_size,
                              hipStream_t stream) {
    const float* u      = (const float*)d_in[0];
    const float* w_in   = (const float*)d_in[1];
    const float* w      = (const float*)d_in[2];
    const float* w_bias = (const float*)d_in[3];
    float* out          = (float*)d_out;
    unsigned int* flags = (unsigned int*)d_ws;

    // zero the 4x64 producer flags every call (ws is poisoned once, never re-poisoned)
    hipMemsetAsync(flags, 0, 4 * 64 * sizeof(unsigned int), stream);

    // 256 WGs x 512 threads: worst-case packing still fits 2 WGs/CU
    // (38 KB LDS, 128 VGPR) so all 256 are co-resident -> flag spin cannot deadlock.
    esn_kernel<<<dim3(NWG), dim3(NTHR), 0, stream>>>(u, w_in, w, w_bias, out, flags);
}